// Round 4
// baseline (166.009 us; speedup 1.0000x reference)
//
#include <hip/hip_runtime.h>
#include <math.h>

#define U 8192
#define NITEMS 100000
#define H 50
#define QD 128
#define D 256
#define BMG 16     // rows per block in the thin GEMMs (grid = U/BMG = 512)
#define NRMAX 13   // max rows per wave in attn: ceil(50/4)

// broadcast block-reduce (256 threads = 4 waves)
__device__ __forceinline__ float block_reduce_256(float v, float* sred) {
    #pragma unroll
    for (int off = 32; off >= 1; off >>= 1)
        v += __shfl_xor(v, off, 64);
    int wave = threadIdx.x >> 6;
    int lane = threadIdx.x & 63;
    if (lane == 0) sred[wave] = v;
    __syncthreads();
    float s;
    if (threadIdx.x == 0) {
        s = sred[0] + sred[1] + sred[2] + sred[3];
        sred[0] = s;
    }
    __syncthreads();
    s = sred[0];
    __syncthreads();
    return s;
}

// Kernel A: M = Wq @ Wk^T [QD,D]; bqt = bq @ Wk^T [D]; wb = Wq @ bk [QD]; c0 = bq.bk
__global__ void __launch_bounds__(256) upa_precompute(
    const float* __restrict__ Wq, const float* __restrict__ bq,
    const float* __restrict__ Wk, const float* __restrict__ bk,
    float* __restrict__ M, float* __restrict__ bqt,
    float* __restrict__ wb, float* __restrict__ c0) {
    __shared__ float row[D];
    __shared__ float sred[4];
    int k = blockIdx.x;
    int t = threadIdx.x;
    if (k < QD) {
        row[t] = (t < D) ? Wq[k * D + t] : 0.f;
        __syncthreads();
        const float4* wkr = (const float4*)(Wk + (size_t)t * D);
        const float4* rr  = (const float4*)row;
        float acc = 0.f;
        #pragma unroll 4
        for (int i = 0; i < D / 4; ++i) {
            float4 a = rr[i]; float4 b = wkr[i];
            acc += a.x * b.x + a.y * b.y + a.z * b.z + a.w * b.w;
        }
        M[k * D + t] = acc;
        float p = row[t] * bk[t];
        float s = block_reduce_256(p, sred);
        if (t == 0) wb[k] = s;
    } else {
        row[t] = bq[t];
        __syncthreads();
        const float4* wkr = (const float4*)(Wk + (size_t)t * D);
        const float4* rr  = (const float4*)row;
        float acc = 0.f;
        #pragma unroll 4
        for (int i = 0; i < D / 4; ++i) {
            float4 a = rr[i]; float4 b = wkr[i];
            acc += a.x * b.x + a.y * b.y + a.z * b.z + a.w * b.w;
        }
        bqt[t] = acc;
        float p = row[t] * bk[t];
        float s = block_reduce_256(p, sred);
        if (t == 0) c0[0] = s;
    }
}

// Kernel B: qt = uq @ M + bqt   [U,D], K=QD. 16 rows/block, K unrolled by 8.
__global__ void __launch_bounds__(256) upa_qt(
    const float* __restrict__ uq, const float* __restrict__ M,
    const float* __restrict__ bqt, float* __restrict__ qt) {
    __shared__ float A[BMG][QD];   // 8 KB
    int u0 = blockIdx.x * BMG;
    int t = threadIdx.x;
    const float4* src = (const float4*)(uq + (size_t)u0 * QD);
    float4* dst = (float4*)&A[0][0];
    for (int i = t; i < BMG * QD / 4; i += 256) dst[i] = src[i];
    __syncthreads();
    float acc[BMG];
    #pragma unroll
    for (int r = 0; r < BMG; ++r) acc[r] = 0.f;
    for (int k8 = 0; k8 < QD; k8 += 8) {
        float m[8];
        #pragma unroll
        for (int i = 0; i < 8; ++i) m[i] = M[(size_t)(k8 + i) * D + t];
        #pragma unroll
        for (int r = 0; r < BMG; ++r) {
            float4 a0 = *((const float4*)&A[r][k8]);
            float4 a1 = *((const float4*)&A[r][k8 + 4]);
            acc[r] += a0.x * m[0] + a0.y * m[1] + a0.z * m[2] + a0.w * m[3]
                    + a1.x * m[4] + a1.y * m[5] + a1.z * m[6] + a1.w * m[7];
        }
    }
    float bb = bqt[t];
    #pragma unroll
    for (int r = 0; r < BMG; ++r) qt[(size_t)(u0 + r) * D + t] = acc[r] + bb;
}

// Kernel C: round-0 remat-friendly two-loop shape + single-pass exp identity.
// 4 waves/user, rows interleaved j = 4*r + wave. Loop 1 issues all 13 b128
// gathers (progressive vmcnt drain); loop 2 consumes — the compiler is FREE
// to reload v[r] from L1 instead of keeping 52 VGPRs live (round-0 behavior,
// WRITE_SIZE stays 8.7 MB; rounds 1-3 proved pins/dbuf cause spills/occ-loss).
// Identity (absmax-identical since r1):
//   w_j = exp(s_j)/(sum_k exp(s_k) + 1e-12*exp(S)),  S = sum_k s_k
// Exactly ONE __syncthreads (final cross-wave combine). launch_bounds(256,8)
// targets full residency: ~40 VGPR fits the 64-VGPR/8-wave budget.
__global__ void __launch_bounds__(256, 8) upa_attn(
    const float* __restrict__ qt, const float* __restrict__ uq,
    const float* __restrict__ wb, const float* __restrict__ c0,
    const float* __restrict__ feats, const int* __restrict__ item_idx,
    float* __restrict__ agg, float* __restrict__ sw) {
    __shared__ float pagg[4][D];    // 4 KB cross-wave partials
    __shared__ float pE[4], pS[4];
    int u = blockIdx.x;
    int t = threadIdx.x;
    int wave = t >> 6, lane = t & 63;

    // per-wave qb = uq[u,:].wb + c0 (butterfly, no barrier)
    float p = uq[(size_t)u * QD + lane] * wb[lane]
            + uq[(size_t)u * QD + 64 + lane] * wb[64 + lane];
    #pragma unroll
    for (int off = 32; off >= 1; off >>= 1)
        p += __shfl_xor(p, off, 64);
    float qb = p + c0[0];

    // full qt row in one b128 per lane
    float4 q = ((const float4*)(qt + (size_t)u * D))[lane];

    // 50 indices live in lanes 0..49; broadcast via readlane (SGPR gather base)
    int ll = lane < H ? lane : H - 1;
    int idxv = item_idx[(size_t)u * H + ll];

    // loop 1: issue all gathers (wave-uniform branch; waves 2,3 have 12 rows)
    float4 v[NRMAX];
    #pragma unroll
    for (int r = 0; r < NRMAX; ++r) {
        int j = 4 * r + wave;
        if (j < H) {
            int sidx = __builtin_amdgcn_readlane(idxv, j);
            v[r] = ((const float4*)(feats + (size_t)sidx * D))[lane];
        }
    }

    // loop 2: score, exp, weighted accumulate (single pass over data)
    float4 acc = make_float4(0.f, 0.f, 0.f, 0.f);
    float E = 0.f, S = 0.f;
    #pragma unroll
    for (int r = 0; r < NRMAX; ++r) {
        int j = 4 * r + wave;
        if (j < H) {
            float part = v[r].x * q.x + v[r].y * q.y + v[r].z * q.z + v[r].w * q.w;
            #pragma unroll
            for (int off = 32; off >= 1; off >>= 1)
                part += __shfl_xor(part, off, 64);
            float s = part + qb;
            float e = __expf(s);
            S += s;
            E += e;
            acc.x += e * v[r].x;
            acc.y += e * v[r].y;
            acc.z += e * v[r].z;
            acc.w += e * v[r].w;
        }
    }

    // cross-wave combine (single barrier in the whole kernel)
    ((float4*)pagg[wave])[lane] = acc;
    if (lane == 0) { pE[wave] = E; pS[wave] = S; }
    __syncthreads();
    float Et = pE[0] + pE[1] + pE[2] + pE[3];
    float St = pS[0] + pS[1] + pS[2] + pS[3];
    float inv = 1.f / (Et + 1e-12f * __expf(St));
    agg[(size_t)u * D + t] =
        (pagg[0][t] + pagg[1][t] + pagg[2][t] + pagg[3][t]) * inv;
    if (t == 0) sw[u] = Et * inv;
}

// Kernel D: out = agg @ Wv + bv * sw[u]   [U,D], K=D. 16 rows/block.
__global__ void __launch_bounds__(256) upa_out(
    const float* __restrict__ agg, const float* __restrict__ Wv,
    const float* __restrict__ bv, const float* __restrict__ sw,
    float* __restrict__ out) {
    __shared__ float A[BMG][D];    // 16 KB
    int u0 = blockIdx.x * BMG;
    int t = threadIdx.x;
    const float4* src = (const float4*)(agg + (size_t)u0 * D);
    float4* dst = (float4*)&A[0][0];
    for (int i = t; i < BMG * D / 4; i += 256) dst[i] = src[i];
    __syncthreads();
    float acc[BMG];
    #pragma unroll
    for (int r = 0; r < BMG; ++r) acc[r] = 0.f;
    for (int k8 = 0; k8 < D; k8 += 8) {
        float m[8];
        #pragma unroll
        for (int i = 0; i < 8; ++i) m[i] = Wv[(size_t)(k8 + i) * D + t];
        #pragma unroll
        for (int r = 0; r < BMG; ++r) {
            float4 a0 = *((const float4*)&A[r][k8]);
            float4 a1 = *((const float4*)&A[r][k8 + 4]);
            acc[r] += a0.x * m[0] + a0.y * m[1] + a0.z * m[2] + a0.w * m[3]
                    + a1.x * m[4] + a1.y * m[5] + a1.z * m[6] + a1.w * m[7];
        }
    }
    float b = bv[t];
    #pragma unroll
    for (int r = 0; r < BMG; ++r)
        out[(size_t)(u0 + r) * D + t] = acc[r] + b * sw[u0 + r];
}

extern "C" void kernel_launch(void* const* d_in, const int* in_sizes, int n_in,
                              void* d_out, int out_size, void* d_ws, size_t ws_size,
                              hipStream_t stream) {
    const float* uq    = (const float*)d_in[0];   // [U,QD]
    const float* feats = (const float*)d_in[1];   // [N,D]
    const float* Wq    = (const float*)d_in[2];   // [QD,D]
    const float* bq    = (const float*)d_in[3];   // [D]
    const float* Wk    = (const float*)d_in[4];   // [D,D]
    const float* bk    = (const float*)d_in[5];   // [D]
    const float* Wv    = (const float*)d_in[6];   // [D,D]
    const float* bv    = (const float*)d_in[7];   // [D]
    // d_in[8] = batch_user_indices: structurally repeat(arange(U),H) -> implicit
    const int* item_idx = (const int*)d_in[9];    // [E]
    float* out = (float*)d_out;

    float* ws  = (float*)d_ws;
    float* M   = ws;                    // QD*D   = 32768
    float* bqt = M + QD * D;            // D      = 256
    float* wb  = bqt + D;               // QD     = 128
    float* c0  = wb + QD;               // 4 (padded)
    float* qt  = c0 + 4;                // U*D    = 2097152
    float* agg = qt + (size_t)U * D;    // U*D    = 2097152
    float* sw  = agg + (size_t)U * D;   // U      = 8192

    upa_precompute<<<QD + 1, 256, 0, stream>>>(Wq, bq, Wk, bk, M, bqt, wb, c0);
    upa_qt<<<U / BMG, 256, 0, stream>>>(uq, M, bqt, qt);
    upa_attn<<<U, 256, 0, stream>>>(qt, uq, wb, c0, feats, item_idx, agg, sw);
    upa_out<<<U / BMG, 256, 0, stream>>>(agg, Wv, bv, sw, out);
}

// Round 5
// 128.244 us; speedup vs baseline: 1.2945x; 1.2945x over previous
//
#include <hip/hip_runtime.h>
#include <math.h>

#define U 8192
#define NITEMS 100000
#define H 50
#define QD 128
#define D 256
#define BMG 16     // rows per block in the thin GEMMs (grid = U/BMG = 512)
#define NRMAX 13   // max rows per wave in attn: ceil(50/4)

// broadcast block-reduce (256 threads = 4 waves)
__device__ __forceinline__ float block_reduce_256(float v, float* sred) {
    #pragma unroll
    for (int off = 32; off >= 1; off >>= 1)
        v += __shfl_xor(v, off, 64);
    int wave = threadIdx.x >> 6;
    int lane = threadIdx.x & 63;
    if (lane == 0) sred[wave] = v;
    __syncthreads();
    float s;
    if (threadIdx.x == 0) {
        s = sred[0] + sred[1] + sred[2] + sred[3];
        sred[0] = s;
    }
    __syncthreads();
    s = sred[0];
    __syncthreads();
    return s;
}

// Kernel A: M = Wq @ Wk^T [QD,D]; bqt = bq @ Wk^T [D]; wb = Wq @ bk [QD]; c0 = bq.bk
__global__ void __launch_bounds__(256) upa_precompute(
    const float* __restrict__ Wq, const float* __restrict__ bq,
    const float* __restrict__ Wk, const float* __restrict__ bk,
    float* __restrict__ M, float* __restrict__ bqt,
    float* __restrict__ wb, float* __restrict__ c0) {
    __shared__ float row[D];
    __shared__ float sred[4];
    int k = blockIdx.x;
    int t = threadIdx.x;
    if (k < QD) {
        row[t] = (t < D) ? Wq[k * D + t] : 0.f;
        __syncthreads();
        const float4* wkr = (const float4*)(Wk + (size_t)t * D);
        const float4* rr  = (const float4*)row;
        float acc = 0.f;
        #pragma unroll 4
        for (int i = 0; i < D / 4; ++i) {
            float4 a = rr[i]; float4 b = wkr[i];
            acc += a.x * b.x + a.y * b.y + a.z * b.z + a.w * b.w;
        }
        M[k * D + t] = acc;
        float p = row[t] * bk[t];
        float s = block_reduce_256(p, sred);
        if (t == 0) wb[k] = s;
    } else {
        row[t] = bq[t];
        __syncthreads();
        const float4* wkr = (const float4*)(Wk + (size_t)t * D);
        const float4* rr  = (const float4*)row;
        float acc = 0.f;
        #pragma unroll 4
        for (int i = 0; i < D / 4; ++i) {
            float4 a = rr[i]; float4 b = wkr[i];
            acc += a.x * b.x + a.y * b.y + a.z * b.z + a.w * b.w;
        }
        bqt[t] = acc;
        float p = row[t] * bk[t];
        float s = block_reduce_256(p, sred);
        if (t == 0) c0[0] = s;
    }
}

// Kernel B: qt = uq @ M + bqt   [U,D], K=QD. 16 rows/block, K unrolled by 8.
__global__ void __launch_bounds__(256) upa_qt(
    const float* __restrict__ uq, const float* __restrict__ M,
    const float* __restrict__ bqt, float* __restrict__ qt) {
    __shared__ float A[BMG][QD];   // 8 KB
    int u0 = blockIdx.x * BMG;
    int t = threadIdx.x;
    const float4* src = (const float4*)(uq + (size_t)u0 * QD);
    float4* dst = (float4*)&A[0][0];
    for (int i = t; i < BMG * QD / 4; i += 256) dst[i] = src[i];
    __syncthreads();
    float acc[BMG];
    #pragma unroll
    for (int r = 0; r < BMG; ++r) acc[r] = 0.f;
    for (int k8 = 0; k8 < QD; k8 += 8) {
        float m[8];
        #pragma unroll
        for (int i = 0; i < 8; ++i) m[i] = M[(size_t)(k8 + i) * D + t];
        #pragma unroll
        for (int r = 0; r < BMG; ++r) {
            float4 a0 = *((const float4*)&A[r][k8]);
            float4 a1 = *((const float4*)&A[r][k8 + 4]);
            acc[r] += a0.x * m[0] + a0.y * m[1] + a0.z * m[2] + a0.w * m[3]
                    + a1.x * m[4] + a1.y * m[5] + a1.z * m[6] + a1.w * m[7];
        }
    }
    float bb = bqt[t];
    #pragma unroll
    for (int r = 0; r < BMG; ++r) qt[(size_t)(u0 + r) * D + t] = acc[r] + bb;
}

// Kernel C: round-0's proven remat-friendly two-loop gather core (bounds
// (256,5), VGPR~36, loads remat from L1 in the accumulate loop — NO pins,
// NO explicit dbuf: rounds 1-4 proved those spill to scratch), with the
// serial overhead stripped:
//   - qb: wave-local butterfly (no barrier)
//   - indices: per-wave register + readlane broadcast (no LDS, no sync)
//   - phase 2: wave-local dual butterfly over the 50 scores -> E,S,inv
//     (redundant per wave, ZERO barriers; identity verified r1-r4:
//      w_j = exp(s_j)/(sum exp + 1e-12*exp(S)))
//   - weights recomputed as exp(s_lds[j])*inv (broadcast read, no 2nd pass)
// Exactly TWO __syncthreads in the whole kernel (scores, final combine),
// vs round-0's eleven.
__global__ void __launch_bounds__(256, 5) upa_attn(
    const float* __restrict__ qt, const float* __restrict__ uq,
    const float* __restrict__ wb, const float* __restrict__ c0,
    const float* __restrict__ feats, const int* __restrict__ item_idx,
    float* __restrict__ agg, float* __restrict__ sw) {
    __shared__ float s_lds[H];
    __shared__ float pagg[4][D];    // 4 KB cross-wave partials
    int u = blockIdx.x;
    int t = threadIdx.x;
    int wave = t >> 6, lane = t & 63;

    // wave-local qb = uq[u,:].wb + c0 (butterfly, no barrier)
    float p = uq[(size_t)u * QD + lane] * wb[lane]
            + uq[(size_t)u * QD + 64 + lane] * wb[64 + lane];
    #pragma unroll
    for (int off = 32; off >= 1; off >>= 1)
        p += __shfl_xor(p, off, 64);
    float qb = p + c0[0];

    // full qt row in one b128 per lane
    float4 q = ((const float4*)(qt + (size_t)u * D))[lane];

    // 50 indices live in lanes 0..49; broadcast via readlane (SGPR base)
    int ll = lane < H ? lane : H - 1;
    int idxv = item_idx[(size_t)u * H + ll];

    // phase 1: issue all gathers, then independent score chains -> s_lds
    float4 v[NRMAX];
    #pragma unroll
    for (int r = 0; r < NRMAX; ++r) {
        int j = 4 * r + wave;
        if (j < H) {
            int sidx = __builtin_amdgcn_readlane(idxv, j);
            v[r] = ((const float4*)(feats + (size_t)sidx * D))[lane];
        }
    }
    #pragma unroll
    for (int r = 0; r < NRMAX; ++r) {
        int j = 4 * r + wave;
        if (j < H) {
            float part = v[r].x * q.x + v[r].y * q.y + v[r].z * q.z + v[r].w * q.w;
            #pragma unroll
            for (int off = 32; off >= 1; off >>= 1)
                part += __shfl_xor(part, off, 64);
            if (lane == 0) s_lds[j] = part + qb;
        }
    }
    __syncthreads();

    // phase 2: wave-local dual butterfly over scores (redundant per wave)
    float sv = (lane < H) ? s_lds[lane] : 0.f;
    float ev = (lane < H) ? __expf(sv) : 0.f;
    float Sv = sv;
    #pragma unroll
    for (int off = 32; off >= 1; off >>= 1) {
        ev += __shfl_xor(ev, off, 64);
        Sv += __shfl_xor(Sv, off, 64);
    }
    float inv = 1.f / (ev + 1e-12f * __expf(Sv));

    // phase 3: weighted accumulate; v[r] remats from L1 (round-0 behavior)
    float4 acc = make_float4(0.f, 0.f, 0.f, 0.f);
    #pragma unroll
    for (int r = 0; r < NRMAX; ++r) {
        int j = 4 * r + wave;
        if (j < H) {
            float w = __expf(s_lds[j]) * inv;   // broadcast LDS read
            acc.x += w * v[r].x;
            acc.y += w * v[r].y;
            acc.z += w * v[r].z;
            acc.w += w * v[r].w;
        }
    }

    // cross-wave combine (second and final barrier)
    ((float4*)pagg[wave])[lane] = acc;
    __syncthreads();
    agg[(size_t)u * D + t] = pagg[0][t] + pagg[1][t] + pagg[2][t] + pagg[3][t];
    if (t == 0) sw[u] = ev * inv;
}

// Kernel D: out = agg @ Wv + bv * sw[u]   [U,D], K=D. 16 rows/block.
__global__ void __launch_bounds__(256) upa_out(
    const float* __restrict__ agg, const float* __restrict__ Wv,
    const float* __restrict__ bv, const float* __restrict__ sw,
    float* __restrict__ out) {
    __shared__ float A[BMG][D];    // 16 KB
    int u0 = blockIdx.x * BMG;
    int t = threadIdx.x;
    const float4* src = (const float4*)(agg + (size_t)u0 * D);
    float4* dst = (float4*)&A[0][0];
    for (int i = t; i < BMG * D / 4; i += 256) dst[i] = src[i];
    __syncthreads();
    float acc[BMG];
    #pragma unroll
    for (int r = 0; r < BMG; ++r) acc[r] = 0.f;
    for (int k8 = 0; k8 < D; k8 += 8) {
        float m[8];
        #pragma unroll
        for (int i = 0; i < 8; ++i) m[i] = Wv[(size_t)(k8 + i) * D + t];
        #pragma unroll
        for (int r = 0; r < BMG; ++r) {
            float4 a0 = *((const float4*)&A[r][k8]);
            float4 a1 = *((const float4*)&A[r][k8 + 4]);
            acc[r] += a0.x * m[0] + a0.y * m[1] + a0.z * m[2] + a0.w * m[3]
                    + a1.x * m[4] + a1.y * m[5] + a1.z * m[6] + a1.w * m[7];
        }
    }
    float b = bv[t];
    #pragma unroll
    for (int r = 0; r < BMG; ++r)
        out[(size_t)(u0 + r) * D + t] = acc[r] + b * sw[u0 + r];
}

extern "C" void kernel_launch(void* const* d_in, const int* in_sizes, int n_in,
                              void* d_out, int out_size, void* d_ws, size_t ws_size,
                              hipStream_t stream) {
    const float* uq    = (const float*)d_in[0];   // [U,QD]
    const float* feats = (const float*)d_in[1];   // [N,D]
    const float* Wq    = (const float*)d_in[2];   // [QD,D]
    const float* bq    = (const float*)d_in[3];   // [D]
    const float* Wk    = (const float*)d_in[4];   // [D,D]
    const float* bk    = (const float*)d_in[5];   // [D]
    const float* Wv    = (const float*)d_in[6];   // [D,D]
    const float* bv    = (const float*)d_in[7];   // [D]
    // d_in[8] = batch_user_indices: structurally repeat(arange(U),H) -> implicit
    const int* item_idx = (const int*)d_in[9];    // [E]
    float* out = (float*)d_out;

    float* ws  = (float*)d_ws;
    float* M   = ws;                    // QD*D   = 32768
    float* bqt = M + QD * D;            // D      = 256
    float* wb  = bqt + D;               // QD     = 128
    float* c0  = wb + QD;               // 4 (padded)
    float* qt  = c0 + 4;                // U*D    = 2097152
    float* agg = qt + (size_t)U * D;    // U*D    = 2097152
    float* sw  = agg + (size_t)U * D;   // U      = 8192

    upa_precompute<<<QD + 1, 256, 0, stream>>>(Wq, bq, Wk, bk, M, bqt, wb, c0);
    upa_qt<<<U / BMG, 256, 0, stream>>>(uq, M, bqt, qt);
    upa_attn<<<U, 256, 0, stream>>>(qt, uq, wb, c0, feats, item_idx, agg, sw);
    upa_out<<<U / BMG, 256, 0, stream>>>(agg, Wv, bv, sw, out);
}

// Round 6
// 125.492 us; speedup vs baseline: 1.3229x; 1.0219x over previous
//
#include <hip/hip_runtime.h>
#include <math.h>

#define U 8192
#define NITEMS 100000
#define H 50
#define QD 128
#define D 256
#define BMG 16     // rows per block in the thin GEMMs (grid = U/BMG = 512)
#define NRMAX 13   // max rows per wave in attn: ceil(50/4)

// Full-wave (64-lane) sum via DPP, result broadcast through readlane(63).
// Chain: quad_perm xor1, xor2 -> row_ror:4, row_ror:8 (row now uniform)
// -> row_bcast:15 (rows 1,3 += prev row) -> row_bcast:31 (rows 2,3 += lane31).
// Lane 63 holds the total. ~6 VALU ops (2-4 cy each) vs 6 DS ops (~40 cy each)
// for __shfl_xor — 8x shorter dependence chain.
__device__ __forceinline__ float wave_bcast_sum64(float x) {
    float t = x;
    int y;
    y = __builtin_amdgcn_update_dpp(0, __float_as_int(t), 0xB1, 0xF, 0xF, true); // quad_perm(1,0,3,2)
    t += __int_as_float(y);
    y = __builtin_amdgcn_update_dpp(0, __float_as_int(t), 0x4E, 0xF, 0xF, true); // quad_perm(2,3,0,1)
    t += __int_as_float(y);
    y = __builtin_amdgcn_update_dpp(0, __float_as_int(t), 0x124, 0xF, 0xF, true); // row_ror:4
    t += __int_as_float(y);
    y = __builtin_amdgcn_update_dpp(0, __float_as_int(t), 0x128, 0xF, 0xF, true); // row_ror:8
    t += __int_as_float(y);
    y = __builtin_amdgcn_update_dpp(0, __float_as_int(t), 0x142, 0xA, 0xF, true); // row_bcast:15
    t += __int_as_float(y);
    y = __builtin_amdgcn_update_dpp(0, __float_as_int(t), 0x143, 0xC, 0xF, true); // row_bcast:31
    t += __int_as_float(y);
    return __int_as_float(__builtin_amdgcn_readlane(__float_as_int(t), 63));
}

// broadcast block-reduce (256 threads = 4 waves) — kernels A only
__device__ __forceinline__ float block_reduce_256(float v, float* sred) {
    #pragma unroll
    for (int off = 32; off >= 1; off >>= 1)
        v += __shfl_xor(v, off, 64);
    int wave = threadIdx.x >> 6;
    int lane = threadIdx.x & 63;
    if (lane == 0) sred[wave] = v;
    __syncthreads();
    float s;
    if (threadIdx.x == 0) {
        s = sred[0] + sred[1] + sred[2] + sred[3];
        sred[0] = s;
    }
    __syncthreads();
    s = sred[0];
    __syncthreads();
    return s;
}

// Kernel A: M = Wq @ Wk^T [QD,D]; bqt = bq @ Wk^T [D]; wb = Wq @ bk [QD]; c0 = bq.bk
__global__ void __launch_bounds__(256) upa_precompute(
    const float* __restrict__ Wq, const float* __restrict__ bq,
    const float* __restrict__ Wk, const float* __restrict__ bk,
    float* __restrict__ M, float* __restrict__ bqt,
    float* __restrict__ wb, float* __restrict__ c0) {
    __shared__ float row[D];
    __shared__ float sred[4];
    int k = blockIdx.x;
    int t = threadIdx.x;
    if (k < QD) {
        row[t] = (t < D) ? Wq[k * D + t] : 0.f;
        __syncthreads();
        const float4* wkr = (const float4*)(Wk + (size_t)t * D);
        const float4* rr  = (const float4*)row;
        float acc = 0.f;
        #pragma unroll 4
        for (int i = 0; i < D / 4; ++i) {
            float4 a = rr[i]; float4 b = wkr[i];
            acc += a.x * b.x + a.y * b.y + a.z * b.z + a.w * b.w;
        }
        M[k * D + t] = acc;
        float p = row[t] * bk[t];
        float s = block_reduce_256(p, sred);
        if (t == 0) wb[k] = s;
    } else {
        row[t] = bq[t];
        __syncthreads();
        const float4* wkr = (const float4*)(Wk + (size_t)t * D);
        const float4* rr  = (const float4*)row;
        float acc = 0.f;
        #pragma unroll 4
        for (int i = 0; i < D / 4; ++i) {
            float4 a = rr[i]; float4 b = wkr[i];
            acc += a.x * b.x + a.y * b.y + a.z * b.z + a.w * b.w;
        }
        bqt[t] = acc;
        float p = row[t] * bk[t];
        float s = block_reduce_256(p, sred);
        if (t == 0) c0[0] = s;
    }
}

// Kernel B: qt = uq @ M + bqt   [U,D], K=QD. 16 rows/block, K unrolled by 8.
__global__ void __launch_bounds__(256) upa_qt(
    const float* __restrict__ uq, const float* __restrict__ M,
    const float* __restrict__ bqt, float* __restrict__ qt) {
    __shared__ float A[BMG][QD];   // 8 KB
    int u0 = blockIdx.x * BMG;
    int t = threadIdx.x;
    const float4* src = (const float4*)(uq + (size_t)u0 * QD);
    float4* dst = (float4*)&A[0][0];
    for (int i = t; i < BMG * QD / 4; i += 256) dst[i] = src[i];
    __syncthreads();
    float acc[BMG];
    #pragma unroll
    for (int r = 0; r < BMG; ++r) acc[r] = 0.f;
    for (int k8 = 0; k8 < QD; k8 += 8) {
        float m[8];
        #pragma unroll
        for (int i = 0; i < 8; ++i) m[i] = M[(size_t)(k8 + i) * D + t];
        #pragma unroll
        for (int r = 0; r < BMG; ++r) {
            float4 a0 = *((const float4*)&A[r][k8]);
            float4 a1 = *((const float4*)&A[r][k8 + 4]);
            acc[r] += a0.x * m[0] + a0.y * m[1] + a0.z * m[2] + a0.w * m[3]
                    + a1.x * m[4] + a1.y * m[5] + a1.z * m[6] + a1.w * m[7];
        }
    }
    float bb = bqt[t];
    #pragma unroll
    for (int r = 0; r < BMG; ++r) qt[(size_t)(u0 + r) * D + t] = acc[r] + bb;
}

// Kernel C: SINGLE-PASS + DPP-reduce. 4 waves/user, rows j = 4*r + wave.
// Per row: gather (readlane SGPR base) -> in-lane dot -> DPP wave-sum
// (~30 cy chain vs ~250 cy for shfl_xor) -> exp -> FMA into acc; the row
// dies immediately, so only ~2 rows need to be live at once (no pins, no
// explicit dbuf — r1-r4 proved those spill). Half the gather instructions
// of the two-pass r0/r5 shape, no s_lds, no phase 2, ONE barrier.
// Identity (absmax-identical r1-r5):
//   w_j = exp(s_j)/(sum_k exp(s_k) + 1e-12*exp(S)),  S = sum_k s_k
__global__ void __launch_bounds__(256, 5) upa_attn(
    const float* __restrict__ qt, const float* __restrict__ uq,
    const float* __restrict__ wb, const float* __restrict__ c0,
    const float* __restrict__ feats, const int* __restrict__ item_idx,
    float* __restrict__ agg, float* __restrict__ sw) {
    __shared__ float pagg[4][D];    // 4 KB cross-wave partials
    __shared__ float pE[4], pS[4];
    int u = blockIdx.x;
    int t = threadIdx.x;
    int wave = t >> 6, lane = t & 63;

    // wave-local qb = uq[u,:].wb + c0 (DPP sum, no barrier)
    float p = uq[(size_t)u * QD + lane] * wb[lane]
            + uq[(size_t)u * QD + 64 + lane] * wb[64 + lane];
    float qb = wave_bcast_sum64(p) + c0[0];

    // full qt row in one b128 per lane
    float4 q = ((const float4*)(qt + (size_t)u * D))[lane];

    // 50 indices live in lanes 0..49; broadcast via readlane (SGPR base)
    int ll = lane < H ? lane : H - 1;
    int idxv = item_idx[(size_t)u * H + ll];

    // single pass: each feats row loaded once, consumed immediately
    float4 acc = make_float4(0.f, 0.f, 0.f, 0.f);
    float E = 0.f, S = 0.f;
    #pragma unroll
    for (int r = 0; r < NRMAX; ++r) {
        int j = 4 * r + wave;
        if (j < H) {
            int sidx = __builtin_amdgcn_readlane(idxv, j);
            float4 v = ((const float4*)(feats + (size_t)sidx * D))[lane];
            float part = v.x * q.x + v.y * q.y + v.z * q.z + v.w * q.w;
            float s = wave_bcast_sum64(part) + qb;
            float e = __expf(s);
            S += s;
            E += e;
            acc.x += e * v.x;
            acc.y += e * v.y;
            acc.z += e * v.z;
            acc.w += e * v.w;
        }
    }

    // cross-wave combine (the only barrier in the kernel)
    ((float4*)pagg[wave])[lane] = acc;
    if (lane == 0) { pE[wave] = E; pS[wave] = S; }
    __syncthreads();
    float Et = pE[0] + pE[1] + pE[2] + pE[3];
    float St = pS[0] + pS[1] + pS[2] + pS[3];
    float inv = 1.f / (Et + 1e-12f * __expf(St));
    agg[(size_t)u * D + t] =
        (pagg[0][t] + pagg[1][t] + pagg[2][t] + pagg[3][t]) * inv;
    if (t == 0) sw[u] = Et * inv;
}

// Kernel D: out = agg @ Wv + bv * sw[u]   [U,D], K=D. 16 rows/block.
__global__ void __launch_bounds__(256) upa_out(
    const float* __restrict__ agg, const float* __restrict__ Wv,
    const float* __restrict__ bv, const float* __restrict__ sw,
    float* __restrict__ out) {
    __shared__ float A[BMG][D];    // 16 KB
    int u0 = blockIdx.x * BMG;
    int t = threadIdx.x;
    const float4* src = (const float4*)(agg + (size_t)u0 * D);
    float4* dst = (float4*)&A[0][0];
    for (int i = t; i < BMG * D / 4; i += 256) dst[i] = src[i];
    __syncthreads();
    float acc[BMG];
    #pragma unroll
    for (int r = 0; r < BMG; ++r) acc[r] = 0.f;
    for (int k8 = 0; k8 < D; k8 += 8) {
        float m[8];
        #pragma unroll
        for (int i = 0; i < 8; ++i) m[i] = Wv[(size_t)(k8 + i) * D + t];
        #pragma unroll
        for (int r = 0; r < BMG; ++r) {
            float4 a0 = *((const float4*)&A[r][k8]);
            float4 a1 = *((const float4*)&A[r][k8 + 4]);
            acc[r] += a0.x * m[0] + a0.y * m[1] + a0.z * m[2] + a0.w * m[3]
                    + a1.x * m[4] + a1.y * m[5] + a1.z * m[6] + a1.w * m[7];
        }
    }
    float b = bv[t];
    #pragma unroll
    for (int r = 0; r < BMG; ++r)
        out[(size_t)(u0 + r) * D + t] = acc[r] + b * sw[u0 + r];
}

extern "C" void kernel_launch(void* const* d_in, const int* in_sizes, int n_in,
                              void* d_out, int out_size, void* d_ws, size_t ws_size,
                              hipStream_t stream) {
    const float* uq    = (const float*)d_in[0];   // [U,QD]
    const float* feats = (const float*)d_in[1];   // [N,D]
    const float* Wq    = (const float*)d_in[2];   // [QD,D]
    const float* bq    = (const float*)d_in[3];   // [D]
    const float* Wk    = (const float*)d_in[4];   // [D,D]
    const float* bk    = (const float*)d_in[5];   // [D]
    const float* Wv    = (const float*)d_in[6];   // [D,D]
    const float* bv    = (const float*)d_in[7];   // [D]
    // d_in[8] = batch_user_indices: structurally repeat(arange(U),H) -> implicit
    const int* item_idx = (const int*)d_in[9];    // [E]
    float* out = (float*)d_out;

    float* ws  = (float*)d_ws;
    float* M   = ws;                    // QD*D   = 32768
    float* bqt = M + QD * D;            // D      = 256
    float* wb  = bqt + D;               // QD     = 128
    float* c0  = wb + QD;               // 4 (padded)
    float* qt  = c0 + 4;                // U*D    = 2097152
    float* agg = qt + (size_t)U * D;    // U*D    = 2097152
    float* sw  = agg + (size_t)U * D;   // U      = 8192

    upa_precompute<<<QD + 1, 256, 0, stream>>>(Wq, bq, Wk, bk, M, bqt, wb, c0);
    upa_qt<<<U / BMG, 256, 0, stream>>>(uq, M, bqt, qt);
    upa_attn<<<U, 256, 0, stream>>>(qt, uq, wb, c0, feats, item_idx, agg, sw);
    upa_out<<<U / BMG, 256, 0, stream>>>(agg, Wv, bv, sw, out);
}

// Round 7
// 122.525 us; speedup vs baseline: 1.3549x; 1.0242x over previous
//
#include <hip/hip_runtime.h>
#include <math.h>

#define U 8192
#define NITEMS 100000
#define H 50
#define QD 128
#define D 256
#define BMG 8      // rows per block in the thin GEMMs (grid = U/BMG = 1024)
                   // r1 (BMG=8) rest≈38µs vs r3/r5/r6 (BMG=16) rest≈52µs:
                   // 1024 blocks -> 4 blocks/CU hides K-loop load latency.
#define NRMAX 13   // max rows per wave in attn: ceil(50/4)

// Full-wave (64-lane) sum via DPP, result broadcast through readlane(63).
// Chain: quad_perm xor1, xor2 -> row_ror:4, row_ror:8 (row now uniform)
// -> row_bcast:15 (rows 1,3 += prev row) -> row_bcast:31 (rows 2,3 += lane31).
// Lane 63 holds the total. ~6 VALU ops (2-4 cy each) vs 6 DS ops (~40 cy each)
// for __shfl_xor — 8x shorter dependence chain.
__device__ __forceinline__ float wave_bcast_sum64(float x) {
    float t = x;
    int y;
    y = __builtin_amdgcn_update_dpp(0, __float_as_int(t), 0xB1, 0xF, 0xF, true); // quad_perm(1,0,3,2)
    t += __int_as_float(y);
    y = __builtin_amdgcn_update_dpp(0, __float_as_int(t), 0x4E, 0xF, 0xF, true); // quad_perm(2,3,0,1)
    t += __int_as_float(y);
    y = __builtin_amdgcn_update_dpp(0, __float_as_int(t), 0x124, 0xF, 0xF, true); // row_ror:4
    t += __int_as_float(y);
    y = __builtin_amdgcn_update_dpp(0, __float_as_int(t), 0x128, 0xF, 0xF, true); // row_ror:8
    t += __int_as_float(y);
    y = __builtin_amdgcn_update_dpp(0, __float_as_int(t), 0x142, 0xA, 0xF, true); // row_bcast:15
    t += __int_as_float(y);
    y = __builtin_amdgcn_update_dpp(0, __float_as_int(t), 0x143, 0xC, 0xF, true); // row_bcast:31
    t += __int_as_float(y);
    return __int_as_float(__builtin_amdgcn_readlane(__float_as_int(t), 63));
}

// broadcast block-reduce (256 threads = 4 waves) — kernel A only
__device__ __forceinline__ float block_reduce_256(float v, float* sred) {
    #pragma unroll
    for (int off = 32; off >= 1; off >>= 1)
        v += __shfl_xor(v, off, 64);
    int wave = threadIdx.x >> 6;
    int lane = threadIdx.x & 63;
    if (lane == 0) sred[wave] = v;
    __syncthreads();
    float s;
    if (threadIdx.x == 0) {
        s = sred[0] + sred[1] + sred[2] + sred[3];
        sred[0] = s;
    }
    __syncthreads();
    s = sred[0];
    __syncthreads();
    return s;
}

// Kernel A: M = Wq @ Wk^T [QD,D]; bqt = bq @ Wk^T [D]; wb = Wq @ bk [QD]; c0 = bq.bk
__global__ void __launch_bounds__(256) upa_precompute(
    const float* __restrict__ Wq, const float* __restrict__ bq,
    const float* __restrict__ Wk, const float* __restrict__ bk,
    float* __restrict__ M, float* __restrict__ bqt,
    float* __restrict__ wb, float* __restrict__ c0) {
    __shared__ float row[D];
    __shared__ float sred[4];
    int k = blockIdx.x;
    int t = threadIdx.x;
    if (k < QD) {
        row[t] = (t < D) ? Wq[k * D + t] : 0.f;
        __syncthreads();
        const float4* wkr = (const float4*)(Wk + (size_t)t * D);
        const float4* rr  = (const float4*)row;
        float acc = 0.f;
        #pragma unroll 4
        for (int i = 0; i < D / 4; ++i) {
            float4 a = rr[i]; float4 b = wkr[i];
            acc += a.x * b.x + a.y * b.y + a.z * b.z + a.w * b.w;
        }
        M[k * D + t] = acc;
        float p = row[t] * bk[t];
        float s = block_reduce_256(p, sred);
        if (t == 0) wb[k] = s;
    } else {
        row[t] = bq[t];
        __syncthreads();
        const float4* wkr = (const float4*)(Wk + (size_t)t * D);
        const float4* rr  = (const float4*)row;
        float acc = 0.f;
        #pragma unroll 4
        for (int i = 0; i < D / 4; ++i) {
            float4 a = rr[i]; float4 b = wkr[i];
            acc += a.x * b.x + a.y * b.y + a.z * b.z + a.w * b.w;
        }
        bqt[t] = acc;
        float p = row[t] * bk[t];
        float s = block_reduce_256(p, sred);
        if (t == 0) c0[0] = s;
    }
}

// Kernel B: qt = uq @ M + bqt   [U,D], K=QD. 8 rows/block, K unrolled by 8.
__global__ void __launch_bounds__(256) upa_qt(
    const float* __restrict__ uq, const float* __restrict__ M,
    const float* __restrict__ bqt, float* __restrict__ qt) {
    __shared__ float A[BMG][QD];   // 4 KB
    int u0 = blockIdx.x * BMG;
    int t = threadIdx.x;
    const float4* src = (const float4*)(uq + (size_t)u0 * QD);
    float4* dst = (float4*)&A[0][0];
    for (int i = t; i < BMG * QD / 4; i += 256) dst[i] = src[i];
    __syncthreads();
    float acc[BMG];
    #pragma unroll
    for (int r = 0; r < BMG; ++r) acc[r] = 0.f;
    for (int k8 = 0; k8 < QD; k8 += 8) {
        float m[8];
        #pragma unroll
        for (int i = 0; i < 8; ++i) m[i] = M[(size_t)(k8 + i) * D + t];
        #pragma unroll
        for (int r = 0; r < BMG; ++r) {
            float4 a0 = *((const float4*)&A[r][k8]);
            float4 a1 = *((const float4*)&A[r][k8 + 4]);
            acc[r] += a0.x * m[0] + a0.y * m[1] + a0.z * m[2] + a0.w * m[3]
                    + a1.x * m[4] + a1.y * m[5] + a1.z * m[6] + a1.w * m[7];
        }
    }
    float bb = bqt[t];
    #pragma unroll
    for (int r = 0; r < BMG; ++r) qt[(size_t)(u0 + r) * D + t] = acc[r] + bb;
}

// Kernel C: SINGLE-PASS + DPP-reduce (r6, best measured: 72-75µs, VGPR=32,
// no scratch). 4 waves/user, rows j = 4*r + wave. Per row: gather (readlane
// SGPR base) -> in-lane dot -> DPP wave-sum -> exp -> FMA into acc; row dies
// immediately. At ~205MB L2-miss traffic and ~2.9TB/s sustained random-fill
// this phase is at the gather-path ceiling (r0/r5/r6 all ~73-77µs across
// wildly different structures).
// Identity (absmax-identical r1-r6):
//   w_j = exp(s_j)/(sum_k exp(s_k) + 1e-12*exp(S)),  S = sum_k s_k
__global__ void __launch_bounds__(256, 5) upa_attn(
    const float* __restrict__ qt, const float* __restrict__ uq,
    const float* __restrict__ wb, const float* __restrict__ c0,
    const float* __restrict__ feats, const int* __restrict__ item_idx,
    float* __restrict__ agg, float* __restrict__ sw) {
    __shared__ float pagg[4][D];    // 4 KB cross-wave partials
    __shared__ float pE[4], pS[4];
    int u = blockIdx.x;
    int t = threadIdx.x;
    int wave = t >> 6, lane = t & 63;

    // wave-local qb = uq[u,:].wb + c0 (DPP sum, no barrier)
    float p = uq[(size_t)u * QD + lane] * wb[lane]
            + uq[(size_t)u * QD + 64 + lane] * wb[64 + lane];
    float qb = wave_bcast_sum64(p) + c0[0];

    // full qt row in one b128 per lane
    float4 q = ((const float4*)(qt + (size_t)u * D))[lane];

    // 50 indices live in lanes 0..49; broadcast via readlane (SGPR base)
    int ll = lane < H ? lane : H - 1;
    int idxv = item_idx[(size_t)u * H + ll];

    // single pass: each feats row loaded once, consumed immediately
    float4 acc = make_float4(0.f, 0.f, 0.f, 0.f);
    float E = 0.f, S = 0.f;
    #pragma unroll
    for (int r = 0; r < NRMAX; ++r) {
        int j = 4 * r + wave;
        if (j < H) {
            int sidx = __builtin_amdgcn_readlane(idxv, j);
            float4 v = ((const float4*)(feats + (size_t)sidx * D))[lane];
            float part = v.x * q.x + v.y * q.y + v.z * q.z + v.w * q.w;
            float s = wave_bcast_sum64(part) + qb;
            float e = __expf(s);
            S += s;
            E += e;
            acc.x += e * v.x;
            acc.y += e * v.y;
            acc.z += e * v.z;
            acc.w += e * v.w;
        }
    }

    // cross-wave combine (the only barrier in the kernel)
    ((float4*)pagg[wave])[lane] = acc;
    if (lane == 0) { pE[wave] = E; pS[wave] = S; }
    __syncthreads();
    float Et = pE[0] + pE[1] + pE[2] + pE[3];
    float St = pS[0] + pS[1] + pS[2] + pS[3];
    float inv = 1.f / (Et + 1e-12f * __expf(St));
    agg[(size_t)u * D + t] =
        (pagg[0][t] + pagg[1][t] + pagg[2][t] + pagg[3][t]) * inv;
    if (t == 0) sw[u] = Et * inv;
}

// Kernel D: out = agg @ Wv + bv * sw[u]   [U,D], K=D. 8 rows/block.
__global__ void __launch_bounds__(256) upa_out(
    const float* __restrict__ agg, const float* __restrict__ Wv,
    const float* __restrict__ bv, const float* __restrict__ sw,
    float* __restrict__ out) {
    __shared__ float A[BMG][D];    // 8 KB
    int u0 = blockIdx.x * BMG;
    int t = threadIdx.x;
    const float4* src = (const float4*)(agg + (size_t)u0 * D);
    float4* dst = (float4*)&A[0][0];
    for (int i = t; i < BMG * D / 4; i += 256) dst[i] = src[i];
    __syncthreads();
    float acc[BMG];
    #pragma unroll
    for (int r = 0; r < BMG; ++r) acc[r] = 0.f;
    for (int k8 = 0; k8 < D; k8 += 8) {
        float m[8];
        #pragma unroll
        for (int i = 0; i < 8; ++i) m[i] = Wv[(size_t)(k8 + i) * D + t];
        #pragma unroll
        for (int r = 0; r < BMG; ++r) {
            float4 a0 = *((const float4*)&A[r][k8]);
            float4 a1 = *((const float4*)&A[r][k8 + 4]);
            acc[r] += a0.x * m[0] + a0.y * m[1] + a0.z * m[2] + a0.w * m[3]
                    + a1.x * m[4] + a1.y * m[5] + a1.z * m[6] + a1.w * m[7];
        }
    }
    float b = bv[t];
    #pragma unroll
    for (int r = 0; r < BMG; ++r)
        out[(size_t)(u0 + r) * D + t] = acc[r] + b * sw[u0 + r];
}

extern "C" void kernel_launch(void* const* d_in, const int* in_sizes, int n_in,
                              void* d_out, int out_size, void* d_ws, size_t ws_size,
                              hipStream_t stream) {
    const float* uq    = (const float*)d_in[0];   // [U,QD]
    const float* feats = (const float*)d_in[1];   // [N,D]
    const float* Wq    = (const float*)d_in[2];   // [QD,D]
    const float* bq    = (const float*)d_in[3];   // [D]
    const float* Wk    = (const float*)d_in[4];   // [D,D]
    const float* bk    = (const float*)d_in[5];   // [D]
    const float* Wv    = (const float*)d_in[6];   // [D,D]
    const float* bv    = (const float*)d_in[7];   // [D]
    // d_in[8] = batch_user_indices: structurally repeat(arange(U),H) -> implicit
    const int* item_idx = (const int*)d_in[9];    // [E]
    float* out = (float*)d_out;

    float* ws  = (float*)d_ws;
    float* M   = ws;                    // QD*D   = 32768
    float* bqt = M + QD * D;            // D      = 256
    float* wb  = bqt + D;               // QD     = 128
    float* c0  = wb + QD;               // 4 (padded)
    float* qt  = c0 + 4;                // U*D    = 2097152
    float* agg = qt + (size_t)U * D;    // U*D    = 2097152
    float* sw  = agg + (size_t)U * D;   // U      = 8192

    upa_precompute<<<QD + 1, 256, 0, stream>>>(Wq, bq, Wk, bk, M, bqt, wb, c0);
    upa_qt<<<U / BMG, 256, 0, stream>>>(uq, M, bqt, qt);
    upa_attn<<<U, 256, 0, stream>>>(qt, uq, wb, c0, feats, item_idx, agg, sw);
    upa_out<<<U / BMG, 256, 0, stream>>>(agg, Wv, bv, sw, out);
}